// Round 7
// baseline (1587.373 us; speedup 1.0000x reference)
//
#include <hip/hip_runtime.h>

// Problem constants
#define M_TOK 32000   // B*T tokens
#define DIM   512     // feature dim
#define KCB   1024    // codebook size
#define NQ    8       // quantizer stages
#define BM 64         // tokens per block; block = 64 x 256 cols, 4 waves (64x64 each)
#define KS 16         // K steps of 32

typedef _Float16 f16x8 __attribute__((ext_vector_type(8)));
typedef _Float16 f16x4 __attribute__((ext_vector_type(4)));
typedef float f32x4 __attribute__((ext_vector_type(4)));

__device__ __forceinline__ float wave_reduce_sum(float v) {
#pragma unroll
  for (int off = 32; off > 0; off >>= 1) v += __shfl_xor(v, off, 64);
  return v;
}

// Monotone float->uint mapping: a<b (float) <=> fenc(a)<fenc(b) (uint)
__device__ __forceinline__ unsigned int fenc(float f) {
  unsigned int u = __float_as_uint(f);
  return (u & 0x80000000u) ? ~u : (u | 0x80000000u);
}

__device__ __forceinline__ _Float16 hi16(float v) { return (_Float16)v; }
__device__ __forceinline__ _Float16 lo16(float v, _Float16 h) {
  return (_Float16)(v - (float)h);  // Sterbenz-exact then rn — same as R3/R5
}

struct Split4 { f16x4 h, l; };
__device__ __forceinline__ Split4 split4(float4 v) {
  Split4 s;
  s.h[0] = hi16(v.x); s.l[0] = lo16(v.x, s.h[0]);
  s.h[1] = hi16(v.y); s.l[1] = lo16(v.y, s.h[1]);
  s.h[2] = hi16(v.z); s.l[2] = lo16(v.z, s.h[2]);
  s.h[3] = hi16(v.w); s.l[3] = lo16(v.w, s.h[3]);
  return s;
}

// ---------- init: e2, r2, keys, lossCell, and x -> hi/lo fp16 planes ----------
__global__ __launch_bounds__(256) void rvq_init_kernel(
    const float* __restrict__ x, const float* __restrict__ cb,
    float* __restrict__ e2, float* __restrict__ r2,
    unsigned long long* __restrict__ keys, float* __restrict__ lossCell,
    _Float16* __restrict__ ahi, _Float16* __restrict__ alo) {
  if (blockIdx.x == 0 && threadIdx.x == 0) *lossCell = 0.f;
  for (int i = blockIdx.x * 256 + threadIdx.x; i < M_TOK; i += gridDim.x * 256)
    keys[i] = ~0ull;
  int row = blockIdx.x * 4 + (threadIdx.x >> 6);
  int lane = threadIdx.x & 63;
  if (row < NQ * KCB) {
    const float4* s4 = (const float4*)(cb + (size_t)row * DIM);
    float s = 0.f;
    float4 v = s4[lane];
    s += v.x * v.x + v.y * v.y + v.z * v.z + v.w * v.w;
    v = s4[lane + 64];
    s += v.x * v.x + v.y * v.y + v.z * v.z + v.w * v.w;
    s = wave_reduce_sum(s);
    if (lane == 0) e2[row] = s;
  } else {
    int t = row - NQ * KCB;
    if (t >= M_TOK) return;
    const float4* s4 = (const float4*)(x + (size_t)t * DIM);
    float4 v0 = s4[lane], v1 = s4[lane + 64];
    float s = v0.x * v0.x + v0.y * v0.y + v0.z * v0.z + v0.w * v0.w
            + v1.x * v1.x + v1.y * v1.y + v1.z * v1.z + v1.w * v1.w;
    Split4 s0 = split4(v0), s1 = split4(v1);
    size_t base = (size_t)t * DIM + lane * 4;
    *(f16x4*)(ahi + base) = s0.h;
    *(f16x4*)(alo + base) = s0.l;
    *(f16x4*)(ahi + base + 256) = s1.h;
    *(f16x4*)(alo + base + 256) = s1.l;
    s = wave_reduce_sum(s);
    if (lane == 0) r2[t] = s;
  }
}

// ------- pre-split codebooks to hi/lo fp16 in MFMA-FRAGMENT order (R3) -------
// Fragment (s, F, c): cols F*16..+15, k = c*32 + (lane>>4)*8 + j.
__global__ __launch_bounds__(256) void rvq_split_cb_kernel(
    const float* __restrict__ cb, _Float16* __restrict__ cbhF,
    _Float16* __restrict__ cblF) {
  int gid = blockIdx.x * 256 + threadIdx.x;  // (((s*64+F)*16+c)*64+l)
  int l = gid & 63;
  int c = (gid >> 6) & 15;
  int F = (gid >> 10) & 63;
  int s = gid >> 16;
  if (s >= NQ) return;
  const float* src = cb + (size_t)(s * KCB + F * 16 + (l & 15)) * DIM
                        + c * 32 + (l >> 4) * 8;
  f16x8 h, lo;
#pragma unroll
  for (int j = 0; j < 8; ++j) {
    _Float16 hh = hi16(src[j]);
    h[j] = hh;
    lo[j] = lo16(src[j], hh);
  }
  *(f16x8*)(cbhF + (size_t)gid * 8) = h;
  *(f16x8*)(cblF + (size_t)gid * 8) = lo;
}

// -------- fused distance GEMM + argmin: all-register, zero-barrier --------
__global__ __launch_bounds__(256, 2) void rvq_argmin_kernel(
    const _Float16* __restrict__ ahi,  // [32000][512] residual hi plane
    const _Float16* __restrict__ alo,  // [32000][512] residual lo plane
    const _Float16* __restrict__ cbhF, // stage fragment-ordered hi
    const _Float16* __restrict__ cblF, // stage fragment-ordered lo
    const float* __restrict__ e2,      // [1024]
    const float* __restrict__ r2,      // [32000]
    unsigned long long* __restrict__ keys) {
  const int tid = threadIdx.x;
  const int lane = tid & 63, w = tid >> 6;
  const int l15 = lane & 15, l4 = lane >> 4;
  const int m = blockIdx.x >> 2, nc = blockIdx.x & 3;  // 4 adjacent bids share A
  const int m0 = m * BM, c0 = nc * 256;

  // per-lane fragment base pointers
  const _Float16* aH = ahi + (size_t)(m0 + l15) * DIM + l4 * 8;
  const _Float16* aL = alo + (size_t)(m0 + l15) * DIM + l4 * 8;
  const int Fb = nc * 16 + w * 4;
  const _Float16* bH = cbhF + ((size_t)Fb * 16 * 64 + lane) * 8;
  const _Float16* bL = cblF + ((size_t)Fb * 16 * 64 + lane) * 8;

  f16x8 Ab[2][8], Bb[2][8];
  f32x4 acc[4][4];
#pragma unroll
  for (int a = 0; a < 4; ++a)
#pragma unroll
    for (int b = 0; b < 4; ++b) acc[a][b] = (f32x4){0.f, 0.f, 0.f, 0.f};

  auto loadA = [&](int buf, int ks) {
#pragma unroll
    for (int mf = 0; mf < 4; ++mf) {
      Ab[buf][mf]     = *(const f16x8*)(aH + (size_t)mf * 16 * DIM + ks * 32);
      Ab[buf][4 + mf] = *(const f16x8*)(aL + (size_t)mf * 16 * DIM + ks * 32);
    }
  };
  auto loadB = [&](int buf, int ks) {
#pragma unroll
    for (int nf = 0; nf < 4; ++nf) {
      Bb[buf][nf]     = *(const f16x8*)(bH + (size_t)(nf * 16 + ks) * 512);
      Bb[buf][4 + nf] = *(const f16x8*)(bL + (size_t)(nf * 16 + ks) * 512);
    }
  };
  // 2-deep register prefetch: loads land >= 2 compute phases before use.
  loadA(0, 0); loadB(0, 0);
  loadA(1, 1); loadB(1, 1);
#pragma unroll
  for (int ks = 0; ks < KS; ++ks) {
    const int b = ks & 1;
    __builtin_amdgcn_s_setprio(1);
#pragma unroll
    for (int nf = 0; nf < 4; ++nf) {
#pragma unroll
      for (int mf = 0; mf < 4; ++mf) {  // same order as R3/R5: hh, hl, lh
        acc[mf][nf] = __builtin_amdgcn_mfma_f32_16x16x32_f16(Ab[b][mf], Bb[b][nf], acc[mf][nf], 0, 0, 0);
        acc[mf][nf] = __builtin_amdgcn_mfma_f32_16x16x32_f16(Ab[b][mf], Bb[b][4 + nf], acc[mf][nf], 0, 0, 0);
        acc[mf][nf] = __builtin_amdgcn_mfma_f32_16x16x32_f16(Ab[b][4 + mf], Bb[b][nf], acc[mf][nf], 0, 0, 0);
      }
    }
    __builtin_amdgcn_s_setprio(0);
    if (ks + 2 < KS) { loadA(b, ks + 2); loadB(b, ks + 2); }
  }

  // ---- fold: dist = (r2 - 2*dot) + e2; 16-lane reduce; atomicMin keys ----
  float rv[4][4];
#pragma unroll
  for (int mf = 0; mf < 4; ++mf) {
    float4 q = *(const float4*)(r2 + m0 + mf * 16 + l4 * 4);
    rv[mf][0] = q.x; rv[mf][1] = q.y; rv[mf][2] = q.z; rv[mf][3] = q.w;
  }
  float minv[16];
  int mini[16];
#pragma unroll
  for (int i2 = 0; i2 < 16; ++i2) { minv[i2] = 3.4e38f; mini[i2] = 0; }
#pragma unroll
  for (int nf = 0; nf < 4; ++nf) {
    int col = c0 + w * 64 + nf * 16 + l15;
    float e2v = e2[col];
#pragma unroll
    for (int mf = 0; mf < 4; ++mf) {
#pragma unroll
      for (int rr = 0; rr < 4; ++rr) {
        float d = (rv[mf][rr] - 2.f * acc[mf][nf][rr]) + e2v;
        int ii = mf * 4 + rr;
        if (d < minv[ii]) { minv[ii] = d; mini[ii] = col; }
      }
    }
  }
#pragma unroll
  for (int mf = 0; mf < 4; ++mf) {
#pragma unroll
    for (int rr = 0; rr < 4; ++rr) {
      int ii = mf * 4 + rr;
      float v = minv[ii];
      int ix = mini[ii];
#pragma unroll
      for (int off = 8; off; off >>= 1) {
        float ov = __shfl_xor(v, off, 16);
        int oi = __shfl_xor(ix, off, 16);
        if (ov < v || (ov == v && oi < ix)) { v = ov; ix = oi; }
      }
      if (l15 == 0) {
        int tok = m0 + mf * 16 + l4 * 4 + rr;
        unsigned long long key = ((unsigned long long)fenc(v) << 32) | (unsigned)ix;
        atomicMin(&keys[tok], key);
      }
    }
  }
}

// ------ per-token update: gather, straight-through, loss, next planes ------
__global__ __launch_bounds__(256) void rvq_update_kernel(
    const float* __restrict__ rin, const float* __restrict__ cb,
    unsigned long long* __restrict__ keys,
    float* __restrict__ rout, float* __restrict__ r2out,
    float* __restrict__ idx_out, float* __restrict__ lossCell,
    _Float16* __restrict__ ahi, _Float16* __restrict__ alo) {
  const int wave = threadIdx.x >> 6, lane = threadIdx.x & 63;
  __shared__ float lred[4];
  float lpart = 0.f;
  for (int r = wave; r < 64; r += 4) {
    const int tok = blockIdx.x * 64 + r;
    const unsigned idx = (unsigned)(keys[tok] & 0xffffffffu);
    const float4* rrow = (const float4*)(rin + (size_t)tok * DIM);
    const float4* crow = (const float4*)(cb + (size_t)idx * DIM);
    float4* orow = (float4*)(rout + (size_t)tok * DIM);
    float ssq_t = 0.f, ssq_r = 0.f;
#pragma unroll
    for (int c4 = 0; c4 < 2; ++c4) {
      int c = lane + c4 * 64;
      float4 a = rrow[c], q = crow[c];
      // t = q - r; qst = r + t; r_new = r - qst; loss += t^2  (ref rounding)
      float4 t = make_float4(q.x - a.x, q.y - a.y, q.z - a.z, q.w - a.w);
      float4 qst = make_float4(a.x + t.x, a.y + t.y, a.z + t.z, a.w + t.w);
      float4 rn = make_float4(a.x - qst.x, a.y - qst.y, a.z - qst.z, a.w - qst.w);
      orow[c] = rn;
      Split4 sp = split4(rn);
      *(f16x4*)(ahi + (size_t)tok * DIM + c * 4) = sp.h;
      *(f16x4*)(alo + (size_t)tok * DIM + c * 4) = sp.l;
      ssq_t += t.x * t.x + t.y * t.y + t.z * t.z + t.w * t.w;
      ssq_r += rn.x * rn.x + rn.y * rn.y + rn.z * rn.z + rn.w * rn.w;
    }
    float tot_t = wave_reduce_sum(ssq_t);
    float tot_r = wave_reduce_sum(ssq_r);
    if (lane == 0) {
      idx_out[tok] = (float)idx;
      keys[tok] = ~0ull;  // re-arm for next stage
      r2out[tok] = tot_r;
      lpart += tot_t;
    }
  }
  if (lane == 0) lred[wave] = lpart;
  __syncthreads();
  if (threadIdx.x == 0)
    atomicAdd(lossCell, lred[0] + lred[1] + lred[2] + lred[3]);
}

// ---------------- finalize: out = x - r8, loss scale ----------------
__global__ __launch_bounds__(256) void rvq_finalize_kernel(
    const float* __restrict__ x, float* __restrict__ out,
    const float* __restrict__ lossCell, float* __restrict__ loss_out) {
  size_t i = (size_t)blockIdx.x * 256 + threadIdx.x;
  const size_t n4 = (size_t)M_TOK * DIM / 4;
  if (i < n4) {
    const float4* x4 = (const float4*)x;
    float4* o4 = (float4*)out;
    float4 a = x4[i], r = o4[i];
    o4[i] = make_float4(a.x - r.x, a.y - r.y, a.z - r.z, a.w - r.w);
  }
  if (blockIdx.x == 0 && threadIdx.x == 0) {
    // mean over stages of 1.25*mean_elem(t^2): 1.25 / (8 * 16384000)
    *loss_out = *lossCell * (1.25f / 131072000.f);
  }
}

extern "C" void kernel_launch(void* const* d_in, const int* in_sizes, int n_in,
                              void* d_out, int out_size, void* d_ws, size_t ws_size,
                              hipStream_t stream) {
  const float* x = (const float*)d_in[0];        // [16,2000,512]
  const float* cb = (const float*)d_in[1];       // [8,1024,512]
  float* out = (float*)d_out;                    // quantized region = residual buffer
  float* idx_out = out + (size_t)M_TOK * DIM;    // [8][32000] indices as float
  float* loss_out = idx_out + (size_t)NQ * M_TOK;

  // ws: keys | e2 | r2 | lossCell | cbhF(8M) | cblF(8M) | ahi(31.25M) | alo  (~79 MiB)
  char* wsp = (char*)d_ws;
  unsigned long long* keys = (unsigned long long*)wsp;            // 256000 B
  float* e2 = (float*)(wsp + 262144);
  float* r2 = (float*)(wsp + 294912);
  float* lossCell = (float*)(wsp + 425984);
  _Float16* cbhF = (_Float16*)(wsp + 524288);
  _Float16* cblF = (_Float16*)(wsp + 524288 + 8388608);
  _Float16* ahi = (_Float16*)(wsp + 524288 + 16777216);
  _Float16* alo = ahi + (size_t)M_TOK * DIM;

  {
    int rows = NQ * KCB + M_TOK;  // 40192
    rvq_init_kernel<<<(rows + 3) / 4, 256, 0, stream>>>(x, cb, e2, r2, keys,
                                                        lossCell, ahi, alo);
    rvq_split_cb_kernel<<<NQ * 64 * 16 * 64 / 256, 256, 0, stream>>>(cb, cbhF, cblF);
  }
  float* resbuf = out;
  for (int s = 0; s < NQ; ++s) {
    const float* rin = (s == 0) ? x : resbuf;
    rvq_argmin_kernel<<<(M_TOK / BM) * 4, 256, 0, stream>>>(
        ahi, alo, cbhF + (size_t)s * KCB * DIM, cblF + (size_t)s * KCB * DIM,
        e2 + s * KCB, r2, keys);
    rvq_update_kernel<<<M_TOK / 64, 256, 0, stream>>>(
        rin, cb + (size_t)s * KCB * DIM, keys, resbuf, r2,
        idx_out + (size_t)s * M_TOK, lossCell, ahi, alo);
  }
  rvq_finalize_kernel<<<(M_TOK * DIM / 4 + 255) / 256, 256, 0, stream>>>(
      x, out, lossCell, loss_out);
}

// Round 8
// 1296.805 us; speedup vs baseline: 1.2241x; 1.2241x over previous
//
#include <hip/hip_runtime.h>

// Problem constants
#define M_TOK 32000   // B*T tokens
#define DIM   512     // feature dim
#define KCB   1024    // codebook size
#define NQ    8       // quantizer stages
// 8-phase GEMM tiling: 256x256 block, 8 waves (128x64 each), BK=32, K'=1536.
#define BM 256
#define NITER 24      // 48 K'-tiles of 32, 2 per iteration

typedef _Float16 f16x8 __attribute__((ext_vector_type(8)));
typedef _Float16 f16x4 __attribute__((ext_vector_type(4)));
typedef float f32x4 __attribute__((ext_vector_type(4)));

#define SBAR() __builtin_amdgcn_s_barrier()
#define SFENCE() __builtin_amdgcn_sched_barrier(0)
#define WAIT_VM(N) asm volatile("s_waitcnt vmcnt(" #N ")" ::: "memory")
#define WAIT_LGKM0() asm volatile("s_waitcnt lgkmcnt(0)" ::: "memory")

__device__ __forceinline__ void gload_lds16(const void* g, void* l) {
  __builtin_amdgcn_global_load_lds(
      (const __attribute__((address_space(1))) unsigned int*)g,
      (__attribute__((address_space(3))) unsigned int*)l, 16, 0, 0);
}

__device__ __forceinline__ float wave_reduce_sum(float v) {
#pragma unroll
  for (int off = 32; off > 0; off >>= 1) v += __shfl_xor(v, off, 64);
  return v;
}

// Monotone float->uint mapping: a<b (float) <=> fenc(a)<fenc(b) (uint)
__device__ __forceinline__ unsigned int fenc(float f) {
  unsigned int u = __float_as_uint(f);
  return (u & 0x80000000u) ? ~u : (u | 0x80000000u);
}

__device__ __forceinline__ _Float16 hi16(float v) { return (_Float16)v; }
__device__ __forceinline__ _Float16 lo16(float v, _Float16 h) {
  return (_Float16)(v - (float)h);  // Sterbenz-exact then rn — same as R3-R7
}

struct Split4 { f16x4 h, l; };
__device__ __forceinline__ Split4 split4(float4 v) {
  Split4 s;
  s.h[0] = hi16(v.x); s.l[0] = lo16(v.x, s.h[0]);
  s.h[1] = hi16(v.y); s.l[1] = lo16(v.y, s.h[1]);
  s.h[2] = hi16(v.z); s.l[2] = lo16(v.z, s.h[2]);
  s.h[3] = hi16(v.w); s.l[3] = lo16(v.w, s.h[3]);
  return s;
}

// ---------- init: e2, r2, keys, lossCell, and x -> hi/lo fp16 planes ----------
__global__ __launch_bounds__(256) void rvq_init_kernel(
    const float* __restrict__ x, const float* __restrict__ cb,
    float* __restrict__ e2, float* __restrict__ r2,
    unsigned long long* __restrict__ keys, float* __restrict__ lossCell,
    _Float16* __restrict__ ahi, _Float16* __restrict__ alo) {
  if (blockIdx.x == 0 && threadIdx.x == 0) *lossCell = 0.f;
  for (int i = blockIdx.x * 256 + threadIdx.x; i < M_TOK; i += gridDim.x * 256)
    keys[i] = ~0ull;
  int row = blockIdx.x * 4 + (threadIdx.x >> 6);
  int lane = threadIdx.x & 63;
  if (row < NQ * KCB) {
    const float4* s4 = (const float4*)(cb + (size_t)row * DIM);
    float s = 0.f;
    float4 v = s4[lane];
    s += v.x * v.x + v.y * v.y + v.z * v.z + v.w * v.w;
    v = s4[lane + 64];
    s += v.x * v.x + v.y * v.y + v.z * v.z + v.w * v.w;
    s = wave_reduce_sum(s);
    if (lane == 0) e2[row] = s;
  } else {
    int t = row - NQ * KCB;
    if (t >= M_TOK) return;
    const float4* s4 = (const float4*)(x + (size_t)t * DIM);
    float4 v0 = s4[lane], v1 = s4[lane + 64];
    float s = v0.x * v0.x + v0.y * v0.y + v0.z * v0.z + v0.w * v0.w
            + v1.x * v1.x + v1.y * v1.y + v1.z * v1.z + v1.w * v1.w;
    Split4 s0 = split4(v0), s1 = split4(v1);
    size_t base = (size_t)t * DIM + lane * 4;
    *(f16x4*)(ahi + base) = s0.h;
    *(f16x4*)(alo + base) = s0.l;
    *(f16x4*)(ahi + base + 256) = s1.h;
    *(f16x4*)(alo + base + 256) = s1.l;
    s = wave_reduce_sum(s);
    if (lane == 0) r2[t] = s;
  }
}

// ---- pre-split codebooks into STAGING-ordered hi/lo fp16 half-tiles ----
// Layout: [s8][bt32][nc4][half2][g8][lane64][8 f16]. bt 0..15 = hi tile j,
// bt 16..31 = lo tile j (j = bt&15, orig k = j*32 + (lane>>4)*8).
// g encodes (wc2 = g>>2, nf = g&3); col = nc*256+half*128+wc2*64+nf*16+(l&15).
// A half-tile (4096 f16 = 8 KB) is then a LINEAR 512x16B global_load_lds copy.
__global__ __launch_bounds__(256) void rvq_split_cb_kernel(
    const float* __restrict__ cb, _Float16* __restrict__ cbF) {
  int gid = blockIdx.x * 256 + threadIdx.x;
  int lane = gid & 63;
  int g = (gid >> 6) & 7;
  int half = (gid >> 9) & 1;
  int nc = (gid >> 10) & 3;
  int bt = (gid >> 12) & 31;
  int s = gid >> 17;
  if (s >= NQ) return;
  int col = nc * 256 + half * 128 + (g >> 2) * 64 + (g & 3) * 16 + (lane & 15);
  int ko = (bt & 15) * 32 + (lane >> 4) * 8;
  const float* src = cb + ((size_t)s * KCB + col) * DIM + ko;
  int isLo = bt >> 4;
  f16x8 out;
#pragma unroll
  for (int j = 0; j < 8; ++j) {
    _Float16 h = hi16(src[j]);
    out[j] = isLo ? lo16(src[j], h) : h;
  }
  *(f16x8*)(cbF + (size_t)gid * 8) = out;
}

// -------- fused distance GEMM + argmin: 8-wave, 4-sub-phase, counted vmcnt ----
// K' = 48 tiles of 32: t<16: Ah*Bh, t<32: Ah*Bl, t<48: Al*Bh (sum = hh+hl+lh).
__global__ __launch_bounds__(512, 2) void rvq_argmin_kernel(
    const _Float16* __restrict__ ahi,  // [32000][512] residual hi plane
    const _Float16* __restrict__ alo,  // [32000][512] residual lo plane
    const _Float16* __restrict__ cbFs, // this stage's staging-ordered B (2 MB)
    const float* __restrict__ e2,      // [1024]
    const float* __restrict__ r2,      // [32000]
    unsigned long long* __restrict__ keys) {
  // fragment-ordered half-tiles: [dbuf][kt][half][g 8][lane 64][8 f16] = 8 KB
  __shared__ _Float16 bufA[2][2][2][4096];  // 64 KB
  __shared__ _Float16 bufB[2][2][2][4096];  // 64 KB

  const int tid = threadIdx.x;
  const int lane = tid & 63, w = tid >> 6;
  const int l15 = lane & 15, l4 = lane >> 4;
  const int wr = w >> 2, wc = w & 3;  // 2(M) x 4(N) waves; wave tile 128x64

  // bijective XCD swizzle for 500 blocks (q=62, r=4): 4 col-siblings adjacent
  const int bid = blockIdx.x;
  const int xcd = bid & 7, org = bid >> 3;
  const int wg = ((xcd < 4) ? xcd * 63 : 252 + (xcd - 4) * 62) + org;
  const int m0 = (wg >> 2) * BM;
  const int nc = wg & 3;

  auto stage = [&](int nb, int tIter, int hp) {
    // hp: 0,1 = A halves kt0; 2,3 = B halves kt0; 4..7 same for kt1
    const int ktl = hp >> 2, half = hp & 1, isB = (hp >> 1) & 1;
    const int t = tIter * 2 + ktl;
    const int j = t & 15, p = t >> 4;
    if (!isB) {
      const _Float16* plane = (p == 2) ? alo : ahi;
      const int row = m0 + half * 128 + w * 16 + l15;
      const int ko = j * 32 + l4 * 8;
      gload_lds16(plane + (size_t)row * 512 + ko, &bufA[nb][ktl][half][w * 512]);
    } else {
      const int bt = (p == 1) ? 16 + j : j;
      const _Float16* base = cbFs + (((size_t)(bt * 4 + nc)) * 2 + half) * 4096;
      gload_lds16(base + tid * 8, &bufB[nb][ktl][half][w * 512]);
    }
  };

  f32x4 acc[8][4];
#pragma unroll
  for (int a = 0; a < 8; ++a)
#pragma unroll
    for (int b = 0; b < 4; ++b) acc[a][b] = (f32x4){0.f, 0.f, 0.f, 0.f};

  // prologue: stage iteration 0 (8 half-tiles), wait the kt0 halves only
#pragma unroll
  for (int hp = 0; hp < 8; ++hp) stage(0, 0, hp);
  WAIT_VM(4);
  SBAR();

  for (int it = 0; it < NITER; ++it) {
    const int pb = it & 1, nb = pb ^ 1;
    const int nt = (it + 1 == NITER) ? 0 : it + 1;  // last-iter stage is dead
#pragma unroll
    for (int ph = 0; ph < 4; ++ph) {
      const int kt = ph >> 1, mfh = ph & 1;
      // --- ds-load register subtile (8 x ds_read_b128, lane-contiguous) ---
      const _Float16* As = &bufA[pb][kt][wr][0];
      const _Float16* Bs = &bufB[pb][kt][wc >> 1][0];
      f16x8 af[4], bf[4];
#pragma unroll
      for (int i = 0; i < 4; ++i)
        af[i] = *(const f16x8*)(As + ((mfh * 4 + i) * 64 + lane) * 8);
#pragma unroll
      for (int i = 0; i < 4; ++i)
        bf[i] = *(const f16x8*)(Bs + (((wc & 1) * 4 + i) * 64 + lane) * 8);
      SFENCE();
      // --- stage 2 half-tiles for the next iteration ---
      stage(nb, nt, 2 * ph);
      stage(nb, nt, 2 * ph + 1);
      // --- counted waits: never drain; 4 newest ops stay in flight ---
      if (ph == 1) WAIT_VM(4);   // prev-iter kt1 halves landed
      if (ph == 3) WAIT_VM(4);   // next-iter kt0 halves landed
      SBAR();
      WAIT_LGKM0();
      SFENCE();                  // rule 18: pin MFMA after the wait
      __builtin_amdgcn_s_setprio(1);
#pragma unroll
      for (int j = 0; j < 4; ++j)
#pragma unroll
        for (int i = 0; i < 4; ++i)
          acc[mfh * 4 + i][j] = __builtin_amdgcn_mfma_f32_16x16x32_f16(
              af[i], bf[j], acc[mfh * 4 + i][j], 0, 0, 0);
      __builtin_amdgcn_s_setprio(0);
      SBAR();
    }
  }
  WAIT_VM(0);  // drain dead trailing stages before LDS goes out of scope

  // ---- fold: dist = (r2 - 2*dot) + e2; 16-lane reduce; atomicMin keys ----
  const int colbase = nc * 256 + (wc >> 1) * 128 + (wc & 1) * 64;
  float minv[32];
  int mini[32];
#pragma unroll
  for (int i = 0; i < 32; ++i) { minv[i] = 3.4e38f; mini[i] = 0; }
#pragma unroll
  for (int nf = 0; nf < 4; ++nf) {
    float e2v = e2[colbase + nf * 16 + l15];
    int colg = colbase + nf * 16 + l15;
#pragma unroll
    for (int mf = 0; mf < 8; ++mf) {
      float4 rv = *(const float4*)(r2 + m0 + wr * 128 + mf * 16 + l4 * 4);
      float rva[4] = {rv.x, rv.y, rv.z, rv.w};
#pragma unroll
      for (int rr = 0; rr < 4; ++rr) {
        float d = (rva[rr] - 2.f * acc[mf][nf][rr]) + e2v;
        int ii = mf * 4 + rr;
        if (d < minv[ii]) { minv[ii] = d; mini[ii] = colg; }
      }
    }
  }
#pragma unroll
  for (int mf = 0; mf < 8; ++mf) {
#pragma unroll
    for (int rr = 0; rr < 4; ++rr) {
      int ii = mf * 4 + rr;
      float v = minv[ii];
      int ix = mini[ii];
#pragma unroll
      for (int off = 8; off; off >>= 1) {
        float ov = __shfl_xor(v, off, 16);
        int oi = __shfl_xor(ix, off, 16);
        if (ov < v || (ov == v && oi < ix)) { v = ov; ix = oi; }
      }
      if (l15 == 0) {
        int tok = m0 + wr * 128 + mf * 16 + l4 * 4 + rr;
        unsigned long long key = ((unsigned long long)fenc(v) << 32) | (unsigned)ix;
        atomicMin(&keys[tok], key);
      }
    }
  }
}

// ------ per-token update: gather, straight-through, loss, next planes ------
__global__ __launch_bounds__(256) void rvq_update_kernel(
    const float* __restrict__ rin, const float* __restrict__ cb,
    unsigned long long* __restrict__ keys,
    float* __restrict__ rout, float* __restrict__ r2out,
    float* __restrict__ idx_out, float* __restrict__ lossCell,
    _Float16* __restrict__ ahi, _Float16* __restrict__ alo) {
  const int wave = threadIdx.x >> 6, lane = threadIdx.x & 63;
  __shared__ float lred[4];
  float lpart = 0.f;
  for (int r = wave; r < 64; r += 4) {
    const int tok = blockIdx.x * 64 + r;
    const unsigned idx = (unsigned)(keys[tok] & 0xffffffffu);
    const float4* rrow = (const float4*)(rin + (size_t)tok * DIM);
    const float4* crow = (const float4*)(cb + (size_t)idx * DIM);
    float4* orow = (float4*)(rout + (size_t)tok * DIM);
    float ssq_t = 0.f, ssq_r = 0.f;
#pragma unroll
    for (int c4 = 0; c4 < 2; ++c4) {
      int c = lane + c4 * 64;
      float4 a = rrow[c], q = crow[c];
      // t = q - r; qst = r + t; r_new = r - qst; loss += t^2  (ref rounding)
      float4 t = make_float4(q.x - a.x, q.y - a.y, q.z - a.z, q.w - a.w);
      float4 qst = make_float4(a.x + t.x, a.y + t.y, a.z + t.z, a.w + t.w);
      float4 rn = make_float4(a.x - qst.x, a.y - qst.y, a.z - qst.z, a.w - qst.w);
      orow[c] = rn;
      Split4 sp = split4(rn);
      *(f16x4*)(ahi + (size_t)tok * DIM + c * 4) = sp.h;
      *(f16x4*)(alo + (size_t)tok * DIM + c * 4) = sp.l;
      ssq_t += t.x * t.x + t.y * t.y + t.z * t.z + t.w * t.w;
      ssq_r += rn.x * rn.x + rn.y * rn.y + rn.z * rn.z + rn.w * rn.w;
    }
    float tot_t = wave_reduce_sum(ssq_t);
    float tot_r = wave_reduce_sum(ssq_r);
    if (lane == 0) {
      idx_out[tok] = (float)idx;
      keys[tok] = ~0ull;  // re-arm for next stage
      r2out[tok] = tot_r;
      lpart += tot_t;
    }
  }
  if (lane == 0) lred[wave] = lpart;
  __syncthreads();
  if (threadIdx.x == 0)
    atomicAdd(lossCell, lred[0] + lred[1] + lred[2] + lred[3]);
}

// ---------------- finalize: out = x - r8, loss scale ----------------
__global__ __launch_bounds__(256) void rvq_finalize_kernel(
    const float* __restrict__ x, float* __restrict__ out,
    const float* __restrict__ lossCell, float* __restrict__ loss_out) {
  size_t i = (size_t)blockIdx.x * 256 + threadIdx.x;
  const size_t n4 = (size_t)M_TOK * DIM / 4;
  if (i < n4) {
    const float4* x4 = (const float4*)x;
    float4* o4 = (float4*)out;
    float4 a = x4[i], r = o4[i];
    o4[i] = make_float4(a.x - r.x, a.y - r.y, a.z - r.z, a.w - r.w);
  }
  if (blockIdx.x == 0 && threadIdx.x == 0) {
    // mean over stages of 1.25*mean_elem(t^2): 1.25 / (8 * 16384000)
    *loss_out = *lossCell * (1.25f / 131072000.f);
  }
}

extern "C" void kernel_launch(void* const* d_in, const int* in_sizes, int n_in,
                              void* d_out, int out_size, void* d_ws, size_t ws_size,
                              hipStream_t stream) {
  const float* x = (const float*)d_in[0];        // [16,2000,512]
  const float* cb = (const float*)d_in[1];       // [8,1024,512]
  float* out = (float*)d_out;                    // quantized region = residual buffer
  float* idx_out = out + (size_t)M_TOK * DIM;    // [8][32000] indices as float
  float* loss_out = idx_out + (size_t)NQ * M_TOK;

  // ws: keys | e2 | r2 | lossCell | cbF (16 MB) | ahi (31.25 MB) | alo
  char* wsp = (char*)d_ws;
  unsigned long long* keys = (unsigned long long*)wsp;            // 256000 B
  float* e2 = (float*)(wsp + 262144);
  float* r2 = (float*)(wsp + 294912);
  float* lossCell = (float*)(wsp + 425984);
  _Float16* cbF = (_Float16*)(wsp + 524288);
  _Float16* ahi = (_Float16*)(wsp + 524288 + 16777216);
  _Float16* alo = ahi + (size_t)M_TOK * DIM;

  {
    int rows = NQ * KCB + M_TOK;  // 40192
    rvq_init_kernel<<<(rows + 3) / 4, 256, 0, stream>>>(x, cb, e2, r2, keys,
                                                        lossCell, ahi, alo);
    rvq_split_cb_kernel<<<(NQ << 17) / 256, 256, 0, stream>>>(cb, cbF);
  }
  float* resbuf = out;
  const size_t stageF = (size_t)1 << 20;  // f16 per stage (2 MB)
  for (int s = 0; s < NQ; ++s) {
    const float* rin = (s == 0) ? x : resbuf;
    rvq_argmin_kernel<<<(M_TOK / BM) * 4, 512, 0, stream>>>(
        ahi, alo, cbF + (size_t)s * stageF, e2 + s * KCB, r2, keys);
    rvq_update_kernel<<<M_TOK / 64, 256, 0, stream>>>(
        rin, cb + (size_t)s * KCB * DIM, keys, resbuf, r2,
        idx_out + (size_t)s * M_TOK, lossCell, ahi, alo);
  }
  rvq_finalize_kernel<<<(M_TOK * DIM / 4 + 255) / 256, 256, 0, stream>>>(
      x, out, lossCell, loss_out);
}

// Round 9
// 1267.407 us; speedup vs baseline: 1.2525x; 1.0232x over previous
//
#include <hip/hip_runtime.h>

// Problem constants
#define M_TOK 32000   // B*T tokens
#define DIM   512     // feature dim
#define KCB   1024    // codebook size
#define NQ    8       // quantizer stages
// Tiling: 256x256 block, 8 waves (128x64 each), K'=48 tiles of 32 (hh|hl|lh).
#define BM 256
#define NT 48

typedef _Float16 f16x8 __attribute__((ext_vector_type(8)));
typedef _Float16 f16x4 __attribute__((ext_vector_type(4)));
typedef float f32x4 __attribute__((ext_vector_type(4)));

#define SBAR() __builtin_amdgcn_s_barrier()
#define SFENCE() __builtin_amdgcn_sched_barrier(0)
#define WAIT_VM(N) asm volatile("s_waitcnt vmcnt(" #N ")" ::: "memory")

__device__ __forceinline__ void gload_lds16(const void* g, void* l) {
  __builtin_amdgcn_global_load_lds(
      (const __attribute__((address_space(1))) unsigned int*)g,
      (__attribute__((address_space(3))) unsigned int*)l, 16, 0, 0);
}

__device__ __forceinline__ float wave_reduce_sum(float v) {
#pragma unroll
  for (int off = 32; off > 0; off >>= 1) v += __shfl_xor(v, off, 64);
  return v;
}

// Monotone float->uint mapping: a<b (float) <=> fenc(a)<fenc(b) (uint)
__device__ __forceinline__ unsigned int fenc(float f) {
  unsigned int u = __float_as_uint(f);
  return (u & 0x80000000u) ? ~u : (u | 0x80000000u);
}

__device__ __forceinline__ _Float16 hi16(float v) { return (_Float16)v; }
__device__ __forceinline__ _Float16 lo16(float v, _Float16 h) {
  return (_Float16)(v - (float)h);  // Sterbenz-exact then rn — same as R3-R8
}

struct Split4 { f16x4 h, l; };
__device__ __forceinline__ Split4 split4(float4 v) {
  Split4 s;
  s.h[0] = hi16(v.x); s.l[0] = lo16(v.x, s.h[0]);
  s.h[1] = hi16(v.y); s.l[1] = lo16(v.y, s.h[1]);
  s.h[2] = hi16(v.z); s.l[2] = lo16(v.z, s.h[2]);
  s.h[3] = hi16(v.w); s.l[3] = lo16(v.w, s.h[3]);
  return s;
}

// ---------- init: e2, r2, keys, lossCell, and x -> hi/lo fp16 planes ----------
__global__ __launch_bounds__(256) void rvq_init_kernel(
    const float* __restrict__ x, const float* __restrict__ cb,
    float* __restrict__ e2, float* __restrict__ r2,
    unsigned long long* __restrict__ keys, float* __restrict__ lossCell,
    _Float16* __restrict__ ahi, _Float16* __restrict__ alo) {
  if (blockIdx.x == 0 && threadIdx.x == 0) *lossCell = 0.f;
  for (int i = blockIdx.x * 256 + threadIdx.x; i < M_TOK; i += gridDim.x * 256)
    keys[i] = ~0ull;
  int row = blockIdx.x * 4 + (threadIdx.x >> 6);
  int lane = threadIdx.x & 63;
  if (row < NQ * KCB) {
    const float4* s4 = (const float4*)(cb + (size_t)row * DIM);
    float s = 0.f;
    float4 v = s4[lane];
    s += v.x * v.x + v.y * v.y + v.z * v.z + v.w * v.w;
    v = s4[lane + 64];
    s += v.x * v.x + v.y * v.y + v.z * v.z + v.w * v.w;
    s = wave_reduce_sum(s);
    if (lane == 0) e2[row] = s;
  } else {
    int t = row - NQ * KCB;
    if (t >= M_TOK) return;
    const float4* s4 = (const float4*)(x + (size_t)t * DIM);
    float4 v0 = s4[lane], v1 = s4[lane + 64];
    float s = v0.x * v0.x + v0.y * v0.y + v0.z * v0.z + v0.w * v0.w
            + v1.x * v1.x + v1.y * v1.y + v1.z * v1.z + v1.w * v1.w;
    Split4 s0 = split4(v0), s1 = split4(v1);
    size_t base = (size_t)t * DIM + lane * 4;
    *(f16x4*)(ahi + base) = s0.h;
    *(f16x4*)(alo + base) = s0.l;
    *(f16x4*)(ahi + base + 256) = s1.h;
    *(f16x4*)(alo + base + 256) = s1.l;
    s = wave_reduce_sum(s);
    if (lane == 0) r2[t] = s;
  }
}

// ---- pre-split codebooks into STAGING-ordered hi/lo fp16 tiles ----
// Layout: [s8][bt32][nc4][c1024][8 f16]. bt 0..15 = hi tile j, 16..31 = lo.
// c = g*64 + l': col = nc*256 + g*16 + (l'&15), k = (bt&15)*32 + (l'>>4)*8.
// One (bt,nc) tile = LINEAR 1024x16B -> exact global_load_lds image.
__global__ __launch_bounds__(256) void rvq_split_cb_kernel(
    const float* __restrict__ cb, _Float16* __restrict__ cbF) {
  int gid = blockIdx.x * 256 + threadIdx.x;
  int c = gid & 1023;
  int nc = (gid >> 10) & 3;
  int bt = (gid >> 12) & 31;
  int s = gid >> 17;
  if (s >= NQ) return;
  int col = nc * 256 + (c >> 6) * 16 + (c & 15);
  int k = (bt & 15) * 32 + ((c >> 4) & 3) * 8;
  const float* src = cb + ((size_t)s * KCB + col) * DIM + k;
  int isLo = bt >> 4;
  f16x8 out;
#pragma unroll
  for (int j = 0; j < 8; ++j) {
    _Float16 h = hi16(src[j]);
    out[j] = isLo ? lo16(src[j], h) : h;
  }
  *(f16x8*)(cbF + (size_t)gid * 8) = out;
}

// -------- fused distance GEMM + argmin: 1 barrier/phase, triple-buffered ----
__global__ __launch_bounds__(512, 1) void rvq_argmin_kernel(
    const _Float16* __restrict__ ahi,  // [32000][512] residual hi plane
    const _Float16* __restrict__ alo,  // [32000][512] residual lo plane
    const _Float16* __restrict__ cbF,  // stage staging-ordered B (2 MB)
    const float* __restrict__ e2,      // [1024]
    const float* __restrict__ r2,      // [32000]
    unsigned long long* __restrict__ keys) {
  __shared__ _Float16 bufA[3][8192];  // 3 x 16 KB
  __shared__ _Float16 bufB[3][8192];  // 3 x 16 KB  (96 KB total)

  const int tid = threadIdx.x;
  const int lane = tid & 63, w = tid >> 6;
  const int l15 = lane & 15, l4 = lane >> 4;
  const int wr = w >> 2, wc = w & 3;  // 2(M) x 4(N); wave tile 128x64

  // bijective XCD swizzle for 500 blocks (q=62, r=4): 4 col-siblings adjacent
  const int bid = blockIdx.x;
  const int xcd = bid & 7, org = bid >> 3;
  const int wg = ((xcd < 4) ? xcd * 63 : 252 + (xcd - 4) * 62) + org;
  const int m0 = (wg >> 2) * BM;
  const int nc = wg & 3;

  // per-thread staging chunks (c0 = tid, c1 = tid+512); wave-uniform-base ok:
  // dest = buf + c*16B = (buf + w*1024) + lane*16.
  const int c0 = tid, c1 = tid + 512;
  const size_t aoff0 = (size_t)(m0 + (c0 >> 6) * 16 + (c0 & 15)) * DIM + ((c0 >> 4) & 3) * 8;
  const size_t aoff1 = (size_t)(m0 + (c1 >> 6) * 16 + (c1 & 15)) * DIM + ((c1 >> 4) & 3) * 8;

  auto stageB = [&](int t, _Float16* dst) {
    int j = t & 15;
    int bt = (t >= 16 && t < 32) ? 16 + j : j;
    const _Float16* src = cbF + (size_t)(bt * 4 + nc) * 8192;
    gload_lds16(src + (size_t)c0 * 8, dst + (size_t)c0 * 8);
    gload_lds16(src + (size_t)c1 * 8, dst + (size_t)c1 * 8);
  };
  auto stageA = [&](int t, _Float16* dst) {
    const _Float16* plane = (t >= 32) ? alo : ahi;
    const int ko = (t & 15) * 32;
    gload_lds16(plane + aoff0 + ko, dst + (size_t)c0 * 8);
    gload_lds16(plane + aoff1 + ko, dst + (size_t)c1 * 8);
  };

  f32x4 acc[8][4];
#pragma unroll
  for (int a = 0; a < 8; ++a)
#pragma unroll
    for (int b = 0; b < 4; ++b) acc[a][b] = (f32x4){0.f, 0.f, 0.f, 0.f};

  // prologue: tiles 0 and 1 in flight; drain tile 0; publish.
  stageB(0, bufB[0]); stageA(0, bufA[0]);
  stageB(1, bufB[1]); stageA(1, bufA[1]);
  WAIT_VM(4);
  SFENCE();
  SBAR();
  SFENCE();

  for (int it6 = 0; it6 < NT; it6 += 6) {
#pragma unroll
    for (int ph = 0; ph < 6; ++ph) {
      const int t = it6 + ph;
      const int rb = ph % 3;          // == t%3 (6 | it6)
      const int wb = (ph + 2) % 3;
      // --- stage tile t+2 (B first: shorter latency headroom needed) ---
      if (t < NT - 2) { stageB(t + 2, bufB[wb]); stageA(t + 2, bufA[wb]); }
      // --- ds-read full wave tile: 8 A-frags + 4 B-frags ---
      const _Float16* As = bufA[rb];
      const _Float16* Bs = bufB[rb];
      f16x8 af[8], bf[4];
#pragma unroll
      for (int mf = 0; mf < 8; ++mf)
        af[mf] = *(const f16x8*)(As + ((size_t)(wr * 8 + mf) * 64 + lane) * 8);
#pragma unroll
      for (int nf = 0; nf < 4; ++nf)
        bf[nf] = *(const f16x8*)(Bs + ((size_t)(wc * 4 + nf) * 64 + lane) * 8);
      // --- counted wait: tile t+1 landed (everyone's, after the barrier);
      //     tile t+2 stays in flight. Tail: drain. ---
      if (t < NT - 2) { WAIT_VM(4); } else { WAIT_VM(0); }
      SFENCE();
      __builtin_amdgcn_s_setprio(1);
#pragma unroll
      for (int nf = 0; nf < 4; ++nf)
#pragma unroll
        for (int mf = 0; mf < 8; ++mf)
          acc[mf][nf] = __builtin_amdgcn_mfma_f32_16x16x32_f16(
              af[mf], bf[nf], acc[mf][nf], 0, 0, 0);
      __builtin_amdgcn_s_setprio(0);
      SFENCE();
      SBAR();
      SFENCE();
    }
  }

  // ---- fold: dist = (r2 - 2*dot) + e2; 16-lane reduce; atomicMin keys ----
  const int colbase = nc * 256 + wc * 64;
  float minv[32];
  int mini[32];
#pragma unroll
  for (int i = 0; i < 32; ++i) { minv[i] = 3.4e38f; mini[i] = 0; }
#pragma unroll
  for (int nf = 0; nf < 4; ++nf) {
    int colg = colbase + nf * 16 + l15;
    float e2v = e2[colg];
#pragma unroll
    for (int mf = 0; mf < 8; ++mf) {
      float4 rv = *(const float4*)(r2 + m0 + wr * 128 + mf * 16 + l4 * 4);
      float rva[4] = {rv.x, rv.y, rv.z, rv.w};
#pragma unroll
      for (int rr = 0; rr < 4; ++rr) {
        float d = (rva[rr] - 2.f * acc[mf][nf][rr]) + e2v;
        int ii = mf * 4 + rr;
        if (d < minv[ii]) { minv[ii] = d; mini[ii] = colg; }
      }
    }
  }
#pragma unroll
  for (int mf = 0; mf < 8; ++mf) {
#pragma unroll
    for (int rr = 0; rr < 4; ++rr) {
      int ii = mf * 4 + rr;
      float v = minv[ii];
      int ix = mini[ii];
#pragma unroll
      for (int off = 8; off; off >>= 1) {
        float ov = __shfl_xor(v, off, 16);
        int oi = __shfl_xor(ix, off, 16);
        if (ov < v || (ov == v && oi < ix)) { v = ov; ix = oi; }
      }
      if (l15 == 0) {
        int tok = m0 + wr * 128 + mf * 16 + l4 * 4 + rr;
        unsigned long long key = ((unsigned long long)fenc(v) << 32) | (unsigned)ix;
        atomicMin(&keys[tok], key);
      }
    }
  }
}

// ------ per-token update: gather, straight-through, loss, next planes ------
__global__ __launch_bounds__(256) void rvq_update_kernel(
    const float* __restrict__ rin, const float* __restrict__ cb,
    unsigned long long* __restrict__ keys,
    float* __restrict__ rout, float* __restrict__ r2out,
    float* __restrict__ idx_out, float* __restrict__ lossCell,
    _Float16* __restrict__ ahi, _Float16* __restrict__ alo) {
  const int wave = threadIdx.x >> 6, lane = threadIdx.x & 63;
  __shared__ float lred[4];
  float lpart = 0.f;
  for (int r = wave; r < 64; r += 4) {
    const int tok = blockIdx.x * 64 + r;
    const unsigned idx = (unsigned)(keys[tok] & 0xffffffffu);
    const float4* rrow = (const float4*)(rin + (size_t)tok * DIM);
    const float4* crow = (const float4*)(cb + (size_t)idx * DIM);
    float4* orow = (float4*)(rout + (size_t)tok * DIM);
    float ssq_t = 0.f, ssq_r = 0.f;
#pragma unroll
    for (int c4 = 0; c4 < 2; ++c4) {
      int c = lane + c4 * 64;
      float4 a = rrow[c], q = crow[c];
      // t = q - r; qst = r + t; r_new = r - qst; loss += t^2  (ref rounding)
      float4 t = make_float4(q.x - a.x, q.y - a.y, q.z - a.z, q.w - a.w);
      float4 qst = make_float4(a.x + t.x, a.y + t.y, a.z + t.z, a.w + t.w);
      float4 rn = make_float4(a.x - qst.x, a.y - qst.y, a.z - qst.z, a.w - qst.w);
      orow[c] = rn;
      Split4 sp = split4(rn);
      *(f16x4*)(ahi + (size_t)tok * DIM + c * 4) = sp.h;
      *(f16x4*)(alo + (size_t)tok * DIM + c * 4) = sp.l;
      ssq_t += t.x * t.x + t.y * t.y + t.z * t.z + t.w * t.w;
      ssq_r += rn.x * rn.x + rn.y * rn.y + rn.z * rn.z + rn.w * rn.w;
    }
    float tot_t = wave_reduce_sum(ssq_t);
    float tot_r = wave_reduce_sum(ssq_r);
    if (lane == 0) {
      idx_out[tok] = (float)idx;
      keys[tok] = ~0ull;  // re-arm for next stage
      r2out[tok] = tot_r;
      lpart += tot_t;
    }
  }
  if (lane == 0) lred[wave] = lpart;
  __syncthreads();
  if (threadIdx.x == 0)
    atomicAdd(lossCell, lred[0] + lred[1] + lred[2] + lred[3]);
}

// ---------------- finalize: out = x - r8, loss scale ----------------
__global__ __launch_bounds__(256) void rvq_finalize_kernel(
    const float* __restrict__ x, float* __restrict__ out,
    const float* __restrict__ lossCell, float* __restrict__ loss_out) {
  size_t i = (size_t)blockIdx.x * 256 + threadIdx.x;
  const size_t n4 = (size_t)M_TOK * DIM / 4;
  if (i < n4) {
    const float4* x4 = (const float4*)x;
    float4* o4 = (float4*)out;
    float4 a = x4[i], r = o4[i];
    o4[i] = make_float4(a.x - r.x, a.y - r.y, a.z - r.z, a.w - r.w);
  }
  if (blockIdx.x == 0 && threadIdx.x == 0) {
    // mean over stages of 1.25*mean_elem(t^2): 1.25 / (8 * 16384000)
    *loss_out = *lossCell * (1.25f / 131072000.f);
  }
}

extern "C" void kernel_launch(void* const* d_in, const int* in_sizes, int n_in,
                              void* d_out, int out_size, void* d_ws, size_t ws_size,
                              hipStream_t stream) {
  const float* x = (const float*)d_in[0];        // [16,2000,512]
  const float* cb = (const float*)d_in[1];       // [8,1024,512]
  float* out = (float*)d_out;                    // quantized region = residual buffer
  float* idx_out = out + (size_t)M_TOK * DIM;    // [8][32000] indices as float
  float* loss_out = idx_out + (size_t)NQ * M_TOK;

  // ws: keys | e2 | r2 | lossCell | cbF (16 MB) | ahi (31.25 MB) | alo
  char* wsp = (char*)d_ws;
  unsigned long long* keys = (unsigned long long*)wsp;            // 256000 B
  float* e2 = (float*)(wsp + 262144);
  float* r2 = (float*)(wsp + 294912);
  float* lossCell = (float*)(wsp + 425984);
  _Float16* cbF = (_Float16*)(wsp + 524288);
  _Float16* ahi = (_Float16*)(wsp + 524288 + 16777216);
  _Float16* alo = ahi + (size_t)M_TOK * DIM;

  {
    int rows = NQ * KCB + M_TOK;  // 40192
    rvq_init_kernel<<<(rows + 3) / 4, 256, 0, stream>>>(x, cb, e2, r2, keys,
                                                        lossCell, ahi, alo);
    rvq_split_cb_kernel<<<(NQ << 17) / 256, 256, 0, stream>>>(cb, cbF);
  }
  float* resbuf = out;
  const size_t stageF = (size_t)1 << 20;  // f16 per stage (2 MB)
  for (int s = 0; s < NQ; ++s) {
    const float* rin = (s == 0) ? x : resbuf;
    rvq_argmin_kernel<<<(M_TOK / BM) * 4, 512, 0, stream>>>(
        ahi, alo, cbF + (size_t)s * stageF, e2 + s * KCB, r2, keys);
    rvq_update_kernel<<<M_TOK / 64, 256, 0, stream>>>(
        rin, cb + (size_t)s * KCB * DIM, keys, resbuf, r2,
        idx_out + (size_t)s * M_TOK, lossCell, ahi, alo);
  }
  rvq_finalize_kernel<<<(M_TOK * DIM / 4 + 255) / 256, 256, 0, stream>>>(
      x, out, lossCell, loss_out);
}

// Round 10
// 1222.267 us; speedup vs baseline: 1.2987x; 1.0369x over previous
//
#include <hip/hip_runtime.h>

// Problem constants
#define M_TOK 32000   // B*T tokens
#define DIM   512     // feature dim
#define KCB   1024    // codebook size
#define NQ    8       // quantizer stages
// Tiling: 256x256 block, 8 waves (128x64 each), 16 j-tiles of k=32,
// fused passes: per j-phase 96 MFMA (hh,hl,lh) from 24 b128 reads.
#define BM 256

typedef _Float16 f16x8 __attribute__((ext_vector_type(8)));
typedef _Float16 f16x4 __attribute__((ext_vector_type(4)));
typedef float f32x4 __attribute__((ext_vector_type(4)));

#define SBAR() __builtin_amdgcn_s_barrier()
#define SFENCE() __builtin_amdgcn_sched_barrier(0)
#define WAIT_VM(N) asm volatile("s_waitcnt vmcnt(" #N ")" ::: "memory")

__device__ __forceinline__ void gload_lds16(const void* g, void* l) {
  __builtin_amdgcn_global_load_lds(
      (const __attribute__((address_space(1))) unsigned int*)g,
      (__attribute__((address_space(3))) unsigned int*)l, 16, 0, 0);
}

__device__ __forceinline__ float wave_reduce_sum(float v) {
#pragma unroll
  for (int off = 32; off > 0; off >>= 1) v += __shfl_xor(v, off, 64);
  return v;
}

// Monotone float->uint mapping: a<b (float) <=> fenc(a)<fenc(b) (uint)
__device__ __forceinline__ unsigned int fenc(float f) {
  unsigned int u = __float_as_uint(f);
  return (u & 0x80000000u) ? ~u : (u | 0x80000000u);
}

__device__ __forceinline__ _Float16 hi16(float v) { return (_Float16)v; }
__device__ __forceinline__ _Float16 lo16(float v, _Float16 h) {
  return (_Float16)(v - (float)h);  // Sterbenz-exact then rn — same as R3-R9
}

struct Split4 { f16x4 h, l; };
__device__ __forceinline__ Split4 split4(float4 v) {
  Split4 s;
  s.h[0] = hi16(v.x); s.l[0] = lo16(v.x, s.h[0]);
  s.h[1] = hi16(v.y); s.l[1] = lo16(v.y, s.h[1]);
  s.h[2] = hi16(v.z); s.l[2] = lo16(v.z, s.h[2]);
  s.h[3] = hi16(v.w); s.l[3] = lo16(v.w, s.h[3]);
  return s;
}

// ---------- init: e2, r2, keys, lossCell, and x -> hi/lo fp16 planes ----------
__global__ __launch_bounds__(256) void rvq_init_kernel(
    const float* __restrict__ x, const float* __restrict__ cb,
    float* __restrict__ e2, float* __restrict__ r2,
    unsigned long long* __restrict__ keys, float* __restrict__ lossCell,
    _Float16* __restrict__ ahi, _Float16* __restrict__ alo) {
  if (blockIdx.x == 0 && threadIdx.x == 0) *lossCell = 0.f;
  for (int i = blockIdx.x * 256 + threadIdx.x; i < M_TOK; i += gridDim.x * 256)
    keys[i] = ~0ull;
  int row = blockIdx.x * 4 + (threadIdx.x >> 6);
  int lane = threadIdx.x & 63;
  if (row < NQ * KCB) {
    const float4* s4 = (const float4*)(cb + (size_t)row * DIM);
    float s = 0.f;
    float4 v = s4[lane];
    s += v.x * v.x + v.y * v.y + v.z * v.z + v.w * v.w;
    v = s4[lane + 64];
    s += v.x * v.x + v.y * v.y + v.z * v.z + v.w * v.w;
    s = wave_reduce_sum(s);
    if (lane == 0) e2[row] = s;
  } else {
    int t = row - NQ * KCB;
    if (t >= M_TOK) return;
    const float4* s4 = (const float4*)(x + (size_t)t * DIM);
    float4 v0 = s4[lane], v1 = s4[lane + 64];
    float s = v0.x * v0.x + v0.y * v0.y + v0.z * v0.z + v0.w * v0.w
            + v1.x * v1.x + v1.y * v1.y + v1.z * v1.z + v1.w * v1.w;
    Split4 s0 = split4(v0), s1 = split4(v1);
    size_t base = (size_t)t * DIM + lane * 4;
    *(f16x4*)(ahi + base) = s0.h;
    *(f16x4*)(alo + base) = s0.l;
    *(f16x4*)(ahi + base + 256) = s1.h;
    *(f16x4*)(alo + base + 256) = s1.l;
    s = wave_reduce_sum(s);
    if (lane == 0) r2[t] = s;
  }
}

// ---- pre-split codebooks into STAGING-ordered hi/lo fp16 tiles ----
// Layout: [s8][bt32][nc4][c1024][8 f16]. bt 0..15 = hi tile j, 16..31 = lo.
// c: col = nc*256 + (c>>6)*16 + (c&15), k = (bt&15)*32 + ((c>>4)&3)*8.
// One (bt,nc) tile = LINEAR 1024x16B -> exact global_load_lds image.
__global__ __launch_bounds__(256) void rvq_split_cb_kernel(
    const float* __restrict__ cb, _Float16* __restrict__ cbF) {
  int gid = blockIdx.x * 256 + threadIdx.x;
  int c = gid & 1023;
  int nc = (gid >> 10) & 3;
  int bt = (gid >> 12) & 31;
  int s = gid >> 17;
  if (s >= NQ) return;
  int col = nc * 256 + (c >> 6) * 16 + (c & 15);
  int k = (bt & 15) * 32 + ((c >> 4) & 3) * 8;
  const float* src = cb + ((size_t)s * KCB + col) * DIM + k;
  int isLo = bt >> 4;
  f16x8 out;
#pragma unroll
  for (int j = 0; j < 8; ++j) {
    _Float16 h = hi16(src[j]);
    out[j] = isLo ? lo16(src[j], h) : h;
  }
  *(f16x8*)(cbF + (size_t)gid * 8) = out;
}

// ---- fused distance GEMM + argmin: fused hh/hl/lh phases, 96 MFMA/phase ----
__global__ __launch_bounds__(512, 1) void rvq_argmin_kernel(
    const _Float16* __restrict__ ahi,  // [32000][512] residual hi plane
    const _Float16* __restrict__ alo,  // [32000][512] residual lo plane
    const _Float16* __restrict__ cbF,  // stage staging-ordered B (2 MB)
    const float* __restrict__ e2,      // [1024]
    const float* __restrict__ r2,      // [32000]
    unsigned long long* __restrict__ keys) {
  __shared__ _Float16 bufA[2][2][8192];  // [dbuf][hi/lo][1024 x 8 f16] 64 KB
  __shared__ _Float16 bufB[2][2][8192];  // 64 KB

  const int tid = threadIdx.x;
  const int lane = tid & 63, w = tid >> 6;
  const int l15 = lane & 15, l4 = lane >> 4;
  const int wr = w >> 2, wc = w & 3;  // 2(M) x 4(N); wave tile 128x64

  // bijective XCD swizzle for 500 blocks (q=62, r=4): 4 col-siblings adjacent
  const int bid = blockIdx.x;
  const int xcd = bid & 7, org = bid >> 3;
  const int wg = ((xcd < 4) ? xcd * 63 : 252 + (xcd - 4) * 62) + org;
  const int m0 = (wg >> 2) * BM;
  const int nc = wg & 3;

  // per-thread staging chunks: q0 = tid, q1 = tid + 512.
  // A tile image [f16][c4][r16]: src row = m0+f*16+r, k = j*32 + c*8.
  const int q0 = tid, q1 = tid + 512;
  const size_t aoff0 = (size_t)(m0 + ((q0 >> 6) << 4) + (q0 & 15)) * DIM + ((q0 >> 4) & 3) * 8;
  const size_t aoff1 = (size_t)(m0 + ((q1 >> 6) << 4) + (q1 & 15)) * DIM + ((q1 >> 4) & 3) * 8;

  auto stageTile = [&](int j, int buf) {
    const int ko = j * 32;
    gload_lds16(ahi + aoff0 + ko, &bufA[buf][0][(size_t)q0 * 8]);
    gload_lds16(ahi + aoff1 + ko, &bufA[buf][0][(size_t)q1 * 8]);
    gload_lds16(alo + aoff0 + ko, &bufA[buf][1][(size_t)q0 * 8]);
    gload_lds16(alo + aoff1 + ko, &bufA[buf][1][(size_t)q1 * 8]);
    const _Float16* bh = cbF + (size_t)(j * 4 + nc) * 8192;
    const _Float16* bl = cbF + (size_t)((16 + j) * 4 + nc) * 8192;
    gload_lds16(bh + (size_t)q0 * 8, &bufB[buf][0][(size_t)q0 * 8]);
    gload_lds16(bh + (size_t)q1 * 8, &bufB[buf][0][(size_t)q1 * 8]);
    gload_lds16(bl + (size_t)q0 * 8, &bufB[buf][1][(size_t)q0 * 8]);
    gload_lds16(bl + (size_t)q1 * 8, &bufB[buf][1][(size_t)q1 * 8]);
  };

  f32x4 acc[8][4];
#pragma unroll
  for (int a = 0; a < 8; ++a)
#pragma unroll
    for (int b = 0; b < 4; ++b) acc[a][b] = (f32x4){0.f, 0.f, 0.f, 0.f};

  stageTile(0, 0);
  for (int j = 0; j < 16; ++j) {
    const int cur = j & 1;
    if (j < 15) {
      stageTile(j + 1, cur ^ 1);
      SFENCE();
      WAIT_VM(8);   // tile j landed (per-wave); j+1's 8 stay in flight
    } else {
      SFENCE();
      WAIT_VM(0);
    }
    SFENCE();
    SBAR();         // all waves' tile-j loads landed -> buf[cur] published
    SFENCE();
    const _Float16* Ah = bufA[cur][0];
    const _Float16* Al = bufA[cur][1];
    const _Float16* Bh = bufB[cur][0];
    const _Float16* Bl = bufB[cur][1];
    f16x8 ah[8], al[8];
#pragma unroll
    for (int mf = 0; mf < 8; ++mf) {
      ah[mf] = *(const f16x8*)(Ah + (size_t)((wr * 8 + mf) * 64 + lane) * 8);
      al[mf] = *(const f16x8*)(Al + (size_t)((wr * 8 + mf) * 64 + lane) * 8);
    }
    __builtin_amdgcn_s_setprio(1);
#pragma unroll
    for (int nf = 0; nf < 4; ++nf) {
      f16x8 bh = *(const f16x8*)(Bh + (size_t)((wc * 4 + nf) * 64 + lane) * 8);
      f16x8 bl = *(const f16x8*)(Bl + (size_t)((wc * 4 + nf) * 64 + lane) * 8);
#pragma unroll
      for (int mf = 0; mf < 8; ++mf)
        acc[mf][nf] = __builtin_amdgcn_mfma_f32_16x16x32_f16(ah[mf], bh, acc[mf][nf], 0, 0, 0);
#pragma unroll
      for (int mf = 0; mf < 8; ++mf)
        acc[mf][nf] = __builtin_amdgcn_mfma_f32_16x16x32_f16(ah[mf], bl, acc[mf][nf], 0, 0, 0);
#pragma unroll
      for (int mf = 0; mf < 8; ++mf)
        acc[mf][nf] = __builtin_amdgcn_mfma_f32_16x16x32_f16(al[mf], bh, acc[mf][nf], 0, 0, 0);
    }
    __builtin_amdgcn_s_setprio(0);
    SFENCE();
    SBAR();         // all reads of buf[cur] consumed before j+2 overwrites
  }

  // ---- fold: dist = (r2 - 2*dot) + e2; 16-lane reduce; atomicMin keys ----
  const int colbase = nc * 256 + wc * 64;
  float minv[32];
  int mini[32];
#pragma unroll
  for (int i = 0; i < 32; ++i) { minv[i] = 3.4e38f; mini[i] = 0; }
#pragma unroll
  for (int nf = 0; nf < 4; ++nf) {
    int colg = colbase + nf * 16 + l15;
    float e2v = e2[colg];
#pragma unroll
    for (int mf = 0; mf < 8; ++mf) {
      float4 rv = *(const float4*)(r2 + m0 + wr * 128 + mf * 16 + l4 * 4);
      float rva[4] = {rv.x, rv.y, rv.z, rv.w};
#pragma unroll
      for (int rr = 0; rr < 4; ++rr) {
        float d = (rva[rr] - 2.f * acc[mf][nf][rr]) + e2v;
        int ii = mf * 4 + rr;
        if (d < minv[ii]) { minv[ii] = d; mini[ii] = colg; }
      }
    }
  }
#pragma unroll
  for (int mf = 0; mf < 8; ++mf) {
#pragma unroll
    for (int rr = 0; rr < 4; ++rr) {
      int ii = mf * 4 + rr;
      float v = minv[ii];
      int ix = mini[ii];
#pragma unroll
      for (int off = 8; off; off >>= 1) {
        float ov = __shfl_xor(v, off, 16);
        int oi = __shfl_xor(ix, off, 16);
        if (ov < v || (ov == v && oi < ix)) { v = ov; ix = oi; }
      }
      if (l15 == 0) {
        int tok = m0 + wr * 128 + mf * 16 + l4 * 4 + rr;
        unsigned long long key = ((unsigned long long)fenc(v) << 32) | (unsigned)ix;
        atomicMin(&keys[tok], key);
      }
    }
  }
}

// ------ per-token update: gather, straight-through, loss, next planes ------
__global__ __launch_bounds__(256) void rvq_update_kernel(
    const float* __restrict__ rin, const float* __restrict__ cb,
    unsigned long long* __restrict__ keys,
    float* __restrict__ rout, float* __restrict__ r2out,
    float* __restrict__ idx_out, float* __restrict__ lossCell,
    _Float16* __restrict__ ahi, _Float16* __restrict__ alo) {
  const int wave = threadIdx.x >> 6, lane = threadIdx.x & 63;
  __shared__ float lred[4];
  float lpart = 0.f;
  for (int r = wave; r < 64; r += 4) {
    const int tok = blockIdx.x * 64 + r;
    const unsigned idx = (unsigned)(keys[tok] & 0xffffffffu);
    const float4* rrow = (const float4*)(rin + (size_t)tok * DIM);
    const float4* crow = (const float4*)(cb + (size_t)idx * DIM);
    float4* orow = (float4*)(rout + (size_t)tok * DIM);
    float ssq_t = 0.f, ssq_r = 0.f;
#pragma unroll
    for (int c4 = 0; c4 < 2; ++c4) {
      int c = lane + c4 * 64;
      float4 a = rrow[c], q = crow[c];
      // t = q - r; qst = r + t; r_new = r - qst; loss += t^2  (ref rounding)
      float4 t = make_float4(q.x - a.x, q.y - a.y, q.z - a.z, q.w - a.w);
      float4 qst = make_float4(a.x + t.x, a.y + t.y, a.z + t.z, a.w + t.w);
      float4 rn = make_float4(a.x - qst.x, a.y - qst.y, a.z - qst.z, a.w - qst.w);
      orow[c] = rn;
      Split4 sp = split4(rn);
      *(f16x4*)(ahi + (size_t)tok * DIM + c * 4) = sp.h;
      *(f16x4*)(alo + (size_t)tok * DIM + c * 4) = sp.l;
      ssq_t += t.x * t.x + t.y * t.y + t.z * t.z + t.w * t.w;
      ssq_r += rn.x * rn.x + rn.y * rn.y + rn.z * rn.z + rn.w * rn.w;
    }
    float tot_t = wave_reduce_sum(ssq_t);
    float tot_r = wave_reduce_sum(ssq_r);
    if (lane == 0) {
      idx_out[tok] = (float)idx;
      keys[tok] = ~0ull;  // re-arm for next stage
      r2out[tok] = tot_r;
      lpart += tot_t;
    }
  }
  if (lane == 0) lred[wave] = lpart;
  __syncthreads();
  if (threadIdx.x == 0)
    atomicAdd(lossCell, lred[0] + lred[1] + lred[2] + lred[3]);
}

// ---------------- finalize: out = x - r8, loss scale ----------------
__global__ __launch_bounds__(256) void rvq_finalize_kernel(
    const float* __restrict__ x, float* __restrict__ out,
    const float* __restrict__ lossCell, float* __restrict__ loss_out) {
  size_t i = (size_t)blockIdx.x * 256 + threadIdx.x;
  const size_t n4 = (size_t)M_TOK * DIM / 4;
  if (i < n4) {
    const float4* x4 = (const float4*)x;
    float4* o4 = (float4*)out;
    float4 a = x4[i], r = o4[i];
    o4[i] = make_float4(a.x - r.x, a.y - r.y, a.z - r.z, a.w - r.w);
  }
  if (blockIdx.x == 0 && threadIdx.x == 0) {
    // mean over stages of 1.25*mean_elem(t^2): 1.25 / (8 * 16384000)
    *loss_out = *lossCell * (1.25f / 131072000.f);
  }
}

extern "C" void kernel_launch(void* const* d_in, const int* in_sizes, int n_in,
                              void* d_out, int out_size, void* d_ws, size_t ws_size,
                              hipStream_t stream) {
  const float* x = (const float*)d_in[0];        // [16,2000,512]
  const float* cb = (const float*)d_in[1];       // [8,1024,512]
  float* out = (float*)d_out;                    // quantized region = residual buffer
  float* idx_out = out + (size_t)M_TOK * DIM;    // [8][32000] indices as float
  float* loss_out = idx_out + (size_t)NQ * M_TOK;

  // ws: keys | e2 | r2 | lossCell | cbF (16 MB) | ahi (31.25 MB) | alo
  char* wsp = (char*)d_ws;
  unsigned long long* keys = (unsigned long long*)wsp;            // 256000 B
  float* e2 = (float*)(wsp + 262144);
  float* r2 = (float*)(wsp + 294912);
  float* lossCell = (float*)(wsp + 425984);
  _Float16* cbF = (_Float16*)(wsp + 524288);
  _Float16* ahi = (_Float16*)(wsp + 524288 + 16777216);
  _Float16* alo = ahi + (size_t)M_TOK * DIM;

  {
    int rows = NQ * KCB + M_TOK;  // 40192
    rvq_init_kernel<<<(rows + 3) / 4, 256, 0, stream>>>(x, cb, e2, r2, keys,
                                                        lossCell, ahi, alo);
    rvq_split_cb_kernel<<<(NQ << 17) / 256, 256, 0, stream>>>(cb, cbF);
  }
  float* resbuf = out;
  const size_t stageF = (size_t)1 << 20;  // f16 per stage (2 MB)
  for (int s = 0; s < NQ; ++s) {
    const float* rin = (s == 0) ? x : resbuf;
    rvq_argmin_kernel<<<(M_TOK / BM) * 4, 512, 0, stream>>>(
        ahi, alo, cbF + (size_t)s * stageF, e2 + s * KCB, r2, keys);
    rvq_update_kernel<<<M_TOK / 64, 256, 0, stream>>>(
        rin, cb + (size_t)s * KCB * DIM, keys, resbuf, r2,
        idx_out + (size_t)s * M_TOK, lossCell, ahi, alo);
  }
  rvq_finalize_kernel<<<(M_TOK * DIM / 4 + 255) / 256, 256, 0, stream>>>(
      x, out, lossCell, loss_out);
}